// Round 2
// baseline (222.896 us; speedup 1.0000x reference)
//
#include <hip/hip_runtime.h>
#include <hip/hip_bf16.h>

#define HWPX 589824          // 768*768
#define MPIX 2359296         // 4*768*768
#define EPSF 1e-7f
#define PX_PER_BLOCK 16384   // 256 threads * 64 px
#define ITERS 16             // 16 iters * (256 threads * 4 px)

// ws float layout:
// [0] cls_bce_sum  [1] cls_inter  [2] cls_sump
// [3] ch0_bce_sum  [4] ch0_inter  [5] ch0_sump
// [6..21]   a_sum[k]   (sum of log1p(-pc)) for pred channels k=1..16
// [22..37]  sum_p[k]
// [38..293] segD[n*16+k]   n=0..15 (ids 1..16)
// [294..549] segP[n*16+k]
// [550..566] cnt[17] as uint32

__device__ __forceinline__ float wave_sum64(float v) {
    #pragma unroll
    for (int o = 32; o; o >>= 1) v += __shfl_xor(v, o, 64);
    return v;
}

__global__ __launch_bounds__(256) void loss_main(
    const float* __restrict__ pred, const float* __restrict__ cls,
    const int* __restrict__ tm, float* __restrict__ acc,
    unsigned* __restrict__ cnt)
{
    __shared__ float binD[17][256];
    __shared__ float binP[17][256];

    const int tid = threadIdx.x;
    const int c = blockIdx.y;          // 0=cls, 1=pred ch0, 2..17=pred ch 1..16
    const long base = (long)blockIdx.x * PX_PER_BLOCK;
    const int b   = (int)(base / HWPX);   // block never straddles a batch (36 blocks/batch)
    const int off = (int)(base % HWPX);

    const int* tptr = tm + (long)b * HWPX + off;
    const float* pptr;
    if (c == 0) pptr = cls + (long)b * HWPX + off;
    else        pptr = pred + ((long)b * 17 + (c - 1)) * (long)HWPX + off;

    if (c >= 2) {
        #pragma unroll
        for (int n = 0; n < 17; ++n) { binD[n][tid] = 0.f; binP[n][tid] = 0.f; }
    } else if (c == 0) {
        unsigned (*cw)[256] = (unsigned(*)[256])binD;
        #pragma unroll
        for (int n = 0; n < 17; ++n) cw[n][tid] = 0u;
    }
    __syncthreads();

    float s0 = 0.f, s1 = 0.f, s2 = 0.f;
    // c>=2: s0 = sum log1p(-pc), s1 = sum p
    // c<2 : s0 = sum (t*logp + (1-t)*log1mp), s1 = sum p*t, s2 = sum p

    for (int it = 0; it < ITERS; ++it) {
        const int o = it * 1024 + tid * 4;
        const float4 p4 = *(const float4*)(pptr + o);
        const int4   t4 = *(const int4*)(tptr + o);
        #pragma unroll
        for (int j = 0; j < 4; ++j) {
            const float p = (j == 0) ? p4.x : (j == 1) ? p4.y : (j == 2) ? p4.z : p4.w;
            const int   t = (j == 0) ? t4.x : (j == 1) ? t4.y : (j == 2) ? t4.z : t4.w;
            const float pc  = fminf(fmaxf(p, EPSF), 1.0f - EPSF);
            const float lp  = __logf(pc);
            const float l1p = __logf(1.0f - pc);   // exact subtraction region, matches log1p(-pc)
            if (c >= 2) {
                s0 += l1p;
                s1 += p;
                const float D = l1p - lp;
                binD[t][tid] += D;
                binP[t][tid] += p;
            } else {
                const bool fg = (c == 0) ? (t > 0) : (t == 0);
                s0 += fg ? lp : l1p;
                s1 += fg ? p : 0.f;
                s2 += p;
                if (c == 0) {
                    unsigned (*cw)[256] = (unsigned(*)[256])binD;
                    cw[t][tid]++;
                }
            }
        }
    }

    // scalar block reduction: butterfly within wave, lane0 of each wave atomics
    s0 = wave_sum64(s0);
    s1 = wave_sum64(s1);
    const int lane = tid & 63;

    if (c >= 2) {
        const int k = c - 2;   // 0..15
        if (lane == 0) {
            atomicAdd(&acc[6 + k], s0);
            atomicAdd(&acc[22 + k], s1);
        }
        __syncthreads();
        for (int s = 128; s > 0; s >>= 1) {
            if (tid < s) {
                #pragma unroll
                for (int n = 0; n < 17; ++n) {
                    binD[n][tid] += binD[n][tid + s];
                    binP[n][tid] += binP[n][tid + s];
                }
            }
            __syncthreads();
        }
        if (tid >= 1 && tid <= 16) {
            atomicAdd(&acc[38 + (tid - 1) * 16 + k], binD[tid][0]);
            atomicAdd(&acc[294 + (tid - 1) * 16 + k], binP[tid][0]);
        }
    } else {
        s2 = wave_sum64(s2);
        const int base3 = (c == 0) ? 0 : 3;
        if (lane == 0) {
            atomicAdd(&acc[base3 + 0], s0);
            atomicAdd(&acc[base3 + 1], s1);
            atomicAdd(&acc[base3 + 2], s2);
        }
        if (c == 0) {
            unsigned (*cw)[256] = (unsigned(*)[256])binD;
            __syncthreads();
            for (int s = 128; s > 0; s >>= 1) {
                if (tid < s) {
                    #pragma unroll
                    for (int n = 0; n < 17; ++n) cw[n][tid] += cw[n][tid + s];
                }
                __syncthreads();
            }
            if (tid < 17) atomicAdd(&cnt[tid], cw[tid][0]);
        }
    }
}

__global__ void loss_final(const float* __restrict__ acc,
                           const unsigned* __restrict__ cnt,
                           float* __restrict__ out)
{
    __shared__ float L[16][16];
    const int tid = threadIdx.x;
    const float Mf = (float)MPIX;

    if (tid < 256) {
        const int n = tid >> 4, k = tid & 15;
        const float A    = -acc[6 + k] / Mf;
        const float segD = acc[38 + n * 16 + k];
        const float segP = acc[294 + n * 16 + k];
        const float sump = acc[22 + k];
        const float cn   = (float)cnt[n + 1];
        const float bce  = A + segD / Mf;
        const float dice = 1.f - (2.f * segP + EPSF) / (sump + cn + EPSF);
        L[n][k] = bce + dice;
    }
    __syncthreads();

    if (tid < 64) {   // wave 0 performs the greedy assignment on lanes 0..15
        const bool mine = (tid < 16);
        float total = 0.f;
        unsigned avail = mine ? 1u : 0u;
        for (int step = 0; step < 16; ++step) {
            float v = (mine && avail) ? L[step][tid] : 1e30f;
            int idx = tid;
            #pragma unroll
            for (int o = 8; o; o >>= 1) {
                const float ov = __shfl_xor(v, o, 64);
                const int   oi = __shfl_xor(idx, o, 64);
                if (ov < v || (ov == v && oi < idx)) { v = ov; idx = oi; }
            }
            if (tid == 0) total += v;
            if (tid == idx) avail = 0;
        }
        if (tid == 0) {
            const float sum_tfg = Mf - (float)cnt[0];
            const float bce_c  = -acc[0] / Mf;
            const float dice_c = 1.f - (2.f * acc[1] + EPSF) / (acc[2] + sum_tfg + EPSF);
            const float bce_0  = -acc[3] / Mf;
            const float dice_0 = 1.f - (2.f * acc[4] + EPSF) / (acc[5] + (float)cnt[0] + EPSF);
            const float res = bce_c + dice_c + bce_0 + dice_0;
            out[0] = (res + total) / 16.f;
        }
    }
}

extern "C" void kernel_launch(void* const* d_in, const int* in_sizes, int n_in,
                              void* d_out, int out_size, void* d_ws, size_t ws_size,
                              hipStream_t stream)
{
    const float* pred = (const float*)d_in[0];
    const float* cls  = (const float*)d_in[1];
    const int*   tmi  = (const int*)d_in[2];
    float*    acc = (float*)d_ws;
    unsigned* cnt = (unsigned*)((char*)d_ws + 550 * sizeof(float));

    hipMemsetAsync(d_ws, 0, (550 + 17) * sizeof(float), stream);

    dim3 grid(MPIX / PX_PER_BLOCK, 18);   // 144 x 18
    loss_main<<<grid, 256, 0, stream>>>(pred, cls, tmi, acc, cnt);
    loss_final<<<1, 256, 0, stream>>>(acc, cnt, (float*)d_out);
}